// Round 3
// baseline (22784.261 us; speedup 1.0000x reference)
//
#include <hip/hip_runtime.h>
#include <hip/hip_cooperative_groups.h>

#define B_  64
#define L_  128
#define H_  1024
#define G4_ 4096
#define T_  256
#define NWG 256

// ---------------------------------------------------------------------------
// helpers: cross-lane exchange
// ---------------------------------------------------------------------------
__device__ __forceinline__ float shx(float v, int m) { return __shfl_xor(v, m, 64); }

template<int CTRL>
__device__ __forceinline__ float dppx(float v) {
    int i = __builtin_bit_cast(int, v);
    i = __builtin_amdgcn_update_dpp(0, i, CTRL, 0xF, 0xF, true);
    return __builtin_bit_cast(float, i);
}

// butterfly stage with accumulator splitting: N accs -> N/2.
// lane keeps half selected by `hi`, exchanges the other half with partner.
template<int N, int CTRL>
__device__ __forceinline__ void rstage_dpp(float* a, bool hi) {
    #pragma unroll
    for (int j = 0; j < N / 2; ++j) {
        float keep = hi ? a[j + N/2] : a[j];
        float send = hi ? a[j]       : a[j + N/2];
        a[j] = keep + dppx<CTRL>(send);
    }
}
template<int N>
__device__ __forceinline__ void rstage_shfl(float* a, bool hi, int mask) {
    #pragma unroll
    for (int j = 0; j < N / 2; ++j) {
        float keep = hi ? a[j + N/2] : a[j];
        float send = hi ? a[j]       : a[j + N/2];
        a[j] = keep + shx(send, mask);
    }
}

// ---------------------------------------------------------------------------
// Kernel 1: hidden[b][j] = b_lin[j] + sum_l latent[b][l] * W_lin[j][l]
// ---------------------------------------------------------------------------
__global__ void hidden_kernel(const float* __restrict__ latent,
                              const float* __restrict__ W_lin,
                              const float* __restrict__ b_lin,
                              float* __restrict__ hidden) {
    const int wave = (blockIdx.x * blockDim.x + threadIdx.x) >> 6;
    const int lane = threadIdx.x & 63;
    for (int o = 0; o < 64; ++o) {
        const int out = wave * 64 + o;
        const int b = out >> 10, j = out & 1023;
        const float2 wv = *(const float2*)(W_lin + j * L_ + lane * 2);
        const float2 xv = *(const float2*)(latent + b * L_ + lane * 2);
        float p = wv.x * xv.x + wv.y * xv.y;
        #pragma unroll
        for (int m = 1; m < 64; m <<= 1) p += shx(p, m);
        if (lane == 0) hidden[out] = p + b_lin[j];
    }
}

// ---------------------------------------------------------------------------
// Kernel 2: x_gates[b][j] = b_ih[j] + b_hh[j] + sum_k hidden[b][k]*W_ih[j][k]
// ---------------------------------------------------------------------------
__global__ void xgates_kernel(const float* __restrict__ hidden,
                              const float* __restrict__ W_ih,
                              const float* __restrict__ b_ih,
                              const float* __restrict__ b_hh,
                              float* __restrict__ x_gates) {
    const int wave = (blockIdx.x * blockDim.x + threadIdx.x) >> 6;
    const int lane = threadIdx.x & 63;
    for (int o = 0; o < 64; ++o) {
        const int out = wave * 64 + o;
        const int b = out >> 12, j = out & 4095;
        float p = 0.f;
        #pragma unroll
        for (int q = 0; q < 4; ++q) {
            const float4 wv = *(const float4*)(W_ih + j * H_ + q * 256 + lane * 4);
            const float4 hv = *(const float4*)(hidden + b * H_ + q * 256 + lane * 4);
            p += wv.x * hv.x + wv.y * hv.y + wv.z * hv.z + wv.w * hv.w;
        }
        #pragma unroll
        for (int m = 1; m < 64; m <<= 1) p += shx(p, m);
        if (lane == 0) x_gates[out] = p + b_ih[j] + b_hh[j];
    }
}

// ---------------------------------------------------------------------------
// Kernel 3: sequential LSTM.
// Grid: 256 WGs = 64 h-slices (hs: 16 h-idx -> 64 gate rows) x 4 batch groups
// (bg: 16 batches). 1024 threads = 16 waves.
// Thread (wv,l): kg=wv&1 (k-half), rg=wv>>1 (8 rows); lane l owns k quads
// {kg*512 + l*4} and {kg*512 + 256 + l*4}  -> weights 16 float4 in VGPRs,
// loaded ONCE. Per step: stage h (16 b x 1024 k = 64 KB) into LDS, 8 passes
// of 2 batches: 4 ds_read_b128 -> 128 FMA -> butterfly reduce (DPP for
// xor1/2, shfl for 4/8/16/32) -> Gl. Elementwise on threads 0..255 with
// c in regs. Global sync = custom atomic barrier (tid0 spins, rest parked).
// ---------------------------------------------------------------------------
__global__ void __launch_bounds__(1024, 4)
lstm_kernel(const float* __restrict__ W_hh,     // [4096][1024]
            const float* __restrict__ x_gates,  // [64][4096]
            const float* __restrict__ W_out,    // [1024]
            float* __restrict__ h_buf,          // [2][64][1024]
            float* __restrict__ part,           // [T][64 b][64 hs]
            int*   __restrict__ bar)            // {cnt, gen}, memset 0
{
    extern __shared__ float smem[];
    float* Hc = smem;            // [16][1024] = 64 KB
    float* Gl = smem + 16384;    // [2][64][17] padded

    const int tid = threadIdx.x;
    const int l   = tid & 63;
    const int wv  = tid >> 6;
    const int kg  = wv & 1;
    const int rg  = wv >> 1;
    const int hs  = blockIdx.x >> 2;
    const int bg  = blockIdx.x & 3;

    // ---- persistent weights: 8 rows x (2 quads of 4 k)
    float4 wA[8], wB[8];
    #pragma unroll
    for (int i = 0; i < 8; ++i) {
        const int r  = rg * 8 + i;                       // local row 0..63
        const int gr = (r >> 4) * H_ + hs * 16 + (r & 15); // gate*H + h-idx
        const float* p = W_hh + (size_t)gr * H_ + kg * 512 + l * 4;
        wA[i] = *(const float4*)(p);
        wB[i] = *(const float4*)(p + 256);
    }

    // ---- elementwise constants (threads 0..255: bb = tid>>4, hi = tid&15)
    const int bb = tid >> 4;
    const int hi = tid & 15;
    const int bG = bg * 16 + bb;
    float xgi = 0, xgf = 0, xgg = 0, xgo = 0, wo = 0;
    if (tid < 256) {
        const float* xg = x_gates + (size_t)bG * G4_ + hs * 16 + hi;
        xgi = xg[0]; xgf = xg[H_]; xgg = xg[2 * H_]; xgo = xg[3 * H_];
        wo  = W_out[hs * 16 + hi];
    }
    float c_state = 0.f;

    const float4* Hc4 = (const float4*)Hc;
    int cur = 0;
    for (int t = 0; t < T_; ++t) {
        // ---- stage this WG's 16 batches of h: global -> LDS (coalesced)
        {
            const float* src = h_buf + cur * (B_ * H_) + (size_t)(bg * 16 + wv) * H_;
            const float4* s4 = (const float4*)src;
            float4 s0 = s4[l], s1 = s4[64 + l], s2 = s4[128 + l], s3 = s4[192 + l];
            float4* dst = (float4*)(Hc + wv * H_);
            dst[l] = s0; dst[64 + l] = s1; dst[128 + l] = s2; dst[192 + l] = s3;
        }
        __syncthreads();

        // ---- 8 passes x 2 batches
        for (int p = 0; p < 8; ++p) {
            float acc[16];   // a = rl*2 + bsel
            const float4 hA0 = Hc4[(p * 2    ) * 256 + kg * 128 + l];
            const float4 hB0 = Hc4[(p * 2    ) * 256 + kg * 128 + 64 + l];
            const float4 hA1 = Hc4[(p * 2 + 1) * 256 + kg * 128 + l];
            const float4 hB1 = Hc4[(p * 2 + 1) * 256 + kg * 128 + 64 + l];
            #pragma unroll
            for (int i = 0; i < 8; ++i) {
                acc[2*i]   = wA[i].x*hA0.x + wA[i].y*hA0.y + wA[i].z*hA0.z + wA[i].w*hA0.w
                           + wB[i].x*hB0.x + wB[i].y*hB0.y + wB[i].z*hB0.z + wB[i].w*hB0.w;
                acc[2*i+1] = wA[i].x*hA1.x + wA[i].y*hA1.y + wA[i].z*hA1.z + wA[i].w*hA1.w
                           + wB[i].x*hB1.x + wB[i].y*hB1.y + wB[i].z*hB1.z + wB[i].w*hB1.w;
            }
            // butterfly reduce over the 64-lane k dimension, splitting accs.
            rstage_dpp<16, 0xB1>(acc, (l & 1) != 0);   // xor 1 (quad_perm, VALU)
            rstage_dpp<8,  0x4E>(acc, (l & 2) != 0);   // xor 2 (quad_perm, VALU)
            rstage_shfl<4>(acc, (l & 4) != 0, 4);      // xor 4
            rstage_shfl<2>(acc, (l & 8) != 0, 8);      // xor 8
            acc[0] += shx(acc[0], 16);                 // xor 16
            acc[0] += shx(acc[0], 32);                 // xor 32
            if (l < 16) {
                const int a  = ((l & 1) << 3) | ((l & 2) << 1) | ((l & 4) >> 1) | ((l & 8) >> 3);
                const int r  = rg * 8 + (a >> 1);
                const int pb = p * 2 + (a & 1);
                Gl[(kg * 64 + r) * 17 + pb] = acc[0];
            }
        }
        __syncthreads();

        // ---- elementwise (one (h-idx, batch) cell per thread 0..255)
        if (tid < 256) {
            const float gi_ = xgi + Gl[(     hi) * 17 + bb] + Gl[(64 +      hi) * 17 + bb];
            const float gf_ = xgf + Gl[(16 + hi) * 17 + bb] + Gl[(64 + 16 + hi) * 17 + bb];
            const float gg_ = xgg + Gl[(32 + hi) * 17 + bb] + Gl[(64 + 32 + hi) * 17 + bb];
            const float go_ = xgo + Gl[(48 + hi) * 17 + bb] + Gl[(64 + 48 + hi) * 17 + bb];
            const float i_ = 1.f / (1.f + expf(-gi_));
            const float f_ = 1.f / (1.f + expf(-gf_));
            const float g_ = tanhf(gg_);
            const float o_ = 1.f / (1.f + expf(-go_));
            c_state = f_ * c_state + i_ * g_;
            const float hv = o_ * tanhf(c_state);
            h_buf[(cur ^ 1) * (B_ * H_) + (size_t)bG * H_ + hs * 16 + hi] = hv;
            float pp = hv * wo;
            pp += shx(pp, 1); pp += shx(pp, 2); pp += shx(pp, 4); pp += shx(pp, 8);
            if (hi == 0) part[((size_t)t * B_ + bG) * 64 + hs] = pp;
        }

        // ---- device-scope barrier (release h writes, arrive, spin on gen)
        __threadfence();
        __syncthreads();
        if (tid == 0) {
            if (__hip_atomic_fetch_add(&bar[0], 1, __ATOMIC_ACQ_REL,
                                       __HIP_MEMORY_SCOPE_AGENT) == NWG - 1) {
                __hip_atomic_store(&bar[0], 0, __ATOMIC_RELAXED, __HIP_MEMORY_SCOPE_AGENT);
                __hip_atomic_store(&bar[1], t + 1, __ATOMIC_RELEASE, __HIP_MEMORY_SCOPE_AGENT);
            } else {
                while (__hip_atomic_load(&bar[1], __ATOMIC_ACQUIRE,
                                         __HIP_MEMORY_SCOPE_AGENT) < t + 1)
                    __builtin_amdgcn_s_sleep(2);
            }
        }
        __syncthreads();
        cur ^= 1;
    }
}

// ---------------------------------------------------------------------------
// Kernel 4: out[b][t] = b_out + sum_hs part[t][b][hs]   (coalesced float4)
// ---------------------------------------------------------------------------
__global__ void out_kernel(const float* __restrict__ part,
                           const float* __restrict__ b_out,
                           float* __restrict__ out) {
    const int g = blockIdx.x * blockDim.x + threadIdx.x;  // 16384
    const int t = g >> 6, b = g & 63;
    const float4* p4 = (const float4*)(part + ((size_t)t * B_ + b) * 64);
    float s = 0.f;
    #pragma unroll
    for (int i = 0; i < 16; ++i) {
        const float4 v = p4[i];
        s += v.x + v.y + v.z + v.w;
    }
    out[b * T_ + t] = s + b_out[0];
}

// ---------------------------------------------------------------------------
extern "C" void kernel_launch(void* const* d_in, const int* in_sizes, int n_in,
                              void* d_out, int out_size, void* d_ws, size_t ws_size,
                              hipStream_t stream) {
    const float* latent = (const float*)d_in[0];
    const float* W_lin  = (const float*)d_in[1];
    const float* b_lin  = (const float*)d_in[2];
    const float* W_ih   = (const float*)d_in[3];
    const float* W_hh   = (const float*)d_in[4];
    const float* b_ih   = (const float*)d_in[5];
    const float* b_hh   = (const float*)d_in[6];
    const float* W_out  = (const float*)d_in[7];
    const float* b_out  = (const float*)d_in[8];

    float* ws      = (float*)d_ws;
    float* hidden  = ws;                   // 65536
    float* x_gates = hidden  + 65536;      // 262144
    float* h_buf   = x_gates + 262144;     // 131072
    float* part    = h_buf   + 131072;     // 1048576
    int*   bar     = (int*)(part + 1048576);
    float* out     = (float*)d_out;

    hipMemsetAsync(h_buf, 0, (size_t)2 * B_ * H_ * sizeof(float), stream);
    hipMemsetAsync(bar, 0, 2 * sizeof(int), stream);

    const int lds_bytes = 98304;  // 64K Hc + 8.5K Gl, padded up to force 1 WG/CU
    hipFuncSetAttribute((const void*)lstm_kernel,
                        hipFuncAttributeMaxDynamicSharedMemorySize, lds_bytes);

    hidden_kernel<<<256, 256, 0, stream>>>(latent, W_lin, b_lin, hidden);
    xgates_kernel<<<1024, 256, 0, stream>>>(hidden, W_ih, b_ih, b_hh, x_gates);

    void* args[] = { (void*)&W_hh, (void*)&x_gates, (void*)&W_out,
                     (void*)&h_buf, (void*)&part, (void*)&bar };
    hipLaunchCooperativeKernel(reinterpret_cast<void*>(lstm_kernel),
                               dim3(NWG), dim3(1024), args, lds_bytes, stream);

    out_kernel<<<64, 256, 0, stream>>>(part, b_out, out);
}

// Round 6
// 3089.015 us; speedup vs baseline: 7.3759x; 7.3759x over previous
//
#include <hip/hip_runtime.h>
#include <hip/hip_cooperative_groups.h>

#define B_  64
#define L_  128
#define H_  1024
#define G4_ 4096
#define T_  256
#define NWG 256

// ---------------------------------------------------------------------------
// helpers: cross-lane exchange
// ---------------------------------------------------------------------------
__device__ __forceinline__ float shx(float v, int m) { return __shfl_xor(v, m, 64); }

template<int CTRL>
__device__ __forceinline__ float dppx(float v) {
    int i = __builtin_bit_cast(int, v);
    i = __builtin_amdgcn_update_dpp(0, i, CTRL, 0xF, 0xF, true);
    return __builtin_bit_cast(float, i);
}

template<int N, int CTRL>
__device__ __forceinline__ void rstage_dpp(float* a, bool hi) {
    #pragma unroll
    for (int j = 0; j < N / 2; ++j) {
        float keep = hi ? a[j + N/2] : a[j];
        float send = hi ? a[j]       : a[j + N/2];
        a[j] = keep + dppx<CTRL>(send);
    }
}
template<int N>
__device__ __forceinline__ void rstage_shfl(float* a, bool hi, int mask) {
    #pragma unroll
    for (int j = 0; j < N / 2; ++j) {
        float keep = hi ? a[j + N/2] : a[j];
        float send = hi ? a[j]       : a[j + N/2];
        a[j] = keep + shx(send, mask);
    }
}

// ---------------------------------------------------------------------------
// Kernel 1: hidden[b][j] = b_lin[j] + sum_l latent[b][l] * W_lin[j][l]
// ---------------------------------------------------------------------------
__global__ void hidden_kernel(const float* __restrict__ latent,
                              const float* __restrict__ W_lin,
                              const float* __restrict__ b_lin,
                              float* __restrict__ hidden) {
    const int wave = (blockIdx.x * blockDim.x + threadIdx.x) >> 6;
    const int lane = threadIdx.x & 63;
    for (int o = 0; o < 64; ++o) {
        const int out = wave * 64 + o;
        const int b = out >> 10, j = out & 1023;
        const float2 wv = *(const float2*)(W_lin + j * L_ + lane * 2);
        const float2 xv = *(const float2*)(latent + b * L_ + lane * 2);
        float p = wv.x * xv.x + wv.y * xv.y;
        #pragma unroll
        for (int m = 1; m < 64; m <<= 1) p += shx(p, m);
        if (lane == 0) hidden[out] = p + b_lin[j];
    }
}

// ---------------------------------------------------------------------------
// Kernel 2: x_gates[b][j] = b_ih[j] + b_hh[j] + sum_k hidden[b][k]*W_ih[j][k]
// ---------------------------------------------------------------------------
__global__ void xgates_kernel(const float* __restrict__ hidden,
                              const float* __restrict__ W_ih,
                              const float* __restrict__ b_ih,
                              const float* __restrict__ b_hh,
                              float* __restrict__ x_gates) {
    const int wave = (blockIdx.x * blockDim.x + threadIdx.x) >> 6;
    const int lane = threadIdx.x & 63;
    for (int o = 0; o < 64; ++o) {
        const int out = wave * 64 + o;
        const int b = out >> 12, j = out & 4095;
        float p = 0.f;
        #pragma unroll
        for (int q = 0; q < 4; ++q) {
            const float4 wv = *(const float4*)(W_ih + j * H_ + q * 256 + lane * 4);
            const float4 hv = *(const float4*)(hidden + b * H_ + q * 256 + lane * 4);
            p += wv.x * hv.x + wv.y * hv.y + wv.z * hv.z + wv.w * hv.w;
        }
        #pragma unroll
        for (int m = 1; m < 64; m <<= 1) p += shx(p, m);
        if (lane == 0) x_gates[out] = p + b_ih[j] + b_hh[j];
    }
}

// ---------------------------------------------------------------------------
// Kernel 3: sequential LSTM.
// Grid: 256 WGs = 64 h-slices (hs) x 4 batch groups (bg, 16 batches each).
// Batch groups are DISJOINT in h -> 4 independent 64-WG barriers.
// All cross-WG h traffic uses RELAXED agent-scope atomics (sc0/sc1: straight
// to coherent LLC, no L2 writeback/invalidate ever). Ordering is
// s_waitcnt vmcnt(0) + monotonic arrival counter, all relaxed.
// Per step: stage h (16 b x 4 KB) LLC->LDS, 8 passes of (4 ds_read_b128 +
// 128 FMA + split-butterfly reduce), elementwise with c in regs.
// ---------------------------------------------------------------------------
__global__ void __launch_bounds__(1024, 4)
lstm_kernel(const float* __restrict__ W_hh,     // [4096][1024]
            const float* __restrict__ x_gates,  // [64][4096]
            const float* __restrict__ W_out,    // [1024]
            float* __restrict__ h_buf,          // [2][64][1024]
            float* __restrict__ part,           // [T][64 b][64 hs]
            int*   __restrict__ bar)            // [4][64] ints, memset 0
{
    extern __shared__ float smem[];
    float* Hc = smem;            // [16][1024] = 64 KB
    float* Gl = smem + 16384;    // [128][17] padded

    const int tid = threadIdx.x;
    const int l   = tid & 63;
    const int wv  = tid >> 6;
    const int kg  = wv & 1;
    const int rg  = wv >> 1;
    const int hs  = blockIdx.x >> 2;
    const int bg  = blockIdx.x & 3;

    // ---- persistent weights: 8 rows x (2 quads of 4 k) in VGPRs
    float4 wA[8], wB[8];
    #pragma unroll
    for (int i = 0; i < 8; ++i) {
        const int r  = rg * 8 + i;
        const int gr = (r >> 4) * H_ + hs * 16 + (r & 15);
        const float* p = W_hh + (size_t)gr * H_ + kg * 512 + l * 4;
        wA[i] = *(const float4*)(p);
        wB[i] = *(const float4*)(p + 256);
    }

    // ---- elementwise constants (threads 0..255: bb = tid>>4, hi = tid&15)
    const int bb = tid >> 4;
    const int hi = tid & 15;
    const int bG = bg * 16 + bb;
    float xgi = 0, xgf = 0, xgg = 0, xgo = 0, wo = 0;
    if (tid < 256) {
        const float* xg = x_gates + (size_t)bG * G4_ + hs * 16 + hi;
        xgi = xg[0]; xgf = xg[H_]; xgg = xg[2 * H_]; xgo = xg[3 * H_];
        wo  = W_out[hs * 16 + hi];
    }
    float c_state = 0.f;

    int* cnt = bar + bg * 64;        // monotonic arrival counter
    int* gen = bar + bg * 64 + 32;   // generation flag (same 256B group line)

    const float4* Hc4 = (const float4*)Hc;
    int cur = 0;
    for (int t = 0; t < T_; ++t) {
        // ---- stage this WG's 16 batches of h: LLC -> LDS (relaxed atomics)
        {
            const unsigned long long* src =
                (const unsigned long long*)(h_buf + cur * (B_ * H_) +
                                            (size_t)(bg * 16 + wv) * H_);
            unsigned long long v[8];
            #pragma unroll
            for (int i = 0; i < 8; ++i)
                v[i] = __hip_atomic_load(src + i * 64 + l, __ATOMIC_RELAXED,
                                         __HIP_MEMORY_SCOPE_AGENT);
            float2* dst2 = (float2*)(Hc + wv * H_);
            #pragma unroll
            for (int i = 0; i < 8; ++i)
                dst2[i * 64 + l] = __builtin_bit_cast(float2, v[i]);
        }
        __syncthreads();

        // ---- 8 passes x 2 batches
        for (int p = 0; p < 8; ++p) {
            float acc[16];
            const float4 hA0 = Hc4[(p * 2    ) * 256 + kg * 128 + l];
            const float4 hB0 = Hc4[(p * 2    ) * 256 + kg * 128 + 64 + l];
            const float4 hA1 = Hc4[(p * 2 + 1) * 256 + kg * 128 + l];
            const float4 hB1 = Hc4[(p * 2 + 1) * 256 + kg * 128 + 64 + l];
            #pragma unroll
            for (int i = 0; i < 8; ++i) {
                acc[2*i]   = wA[i].x*hA0.x + wA[i].y*hA0.y + wA[i].z*hA0.z + wA[i].w*hA0.w
                           + wB[i].x*hB0.x + wB[i].y*hB0.y + wB[i].z*hB0.z + wB[i].w*hB0.w;
                acc[2*i+1] = wA[i].x*hA1.x + wA[i].y*hA1.y + wA[i].z*hA1.z + wA[i].w*hA1.w
                           + wB[i].x*hB1.x + wB[i].y*hB1.y + wB[i].z*hB1.z + wB[i].w*hB1.w;
            }
            rstage_dpp<16, 0xB1>(acc, (l & 1) != 0);   // xor 1 (VALU)
            rstage_dpp<8,  0x4E>(acc, (l & 2) != 0);   // xor 2 (VALU)
            rstage_shfl<4>(acc, (l & 4) != 0, 4);      // xor 4
            rstage_shfl<2>(acc, (l & 8) != 0, 8);      // xor 8
            acc[0] += shx(acc[0], 16);
            acc[0] += shx(acc[0], 32);
            if (l < 16) {
                const int a  = ((l & 1) << 3) | ((l & 2) << 1) | ((l & 4) >> 1) | ((l & 8) >> 3);
                const int r  = rg * 8 + (a >> 1);
                const int pb = p * 2 + (a & 1);
                Gl[(kg * 64 + r) * 17 + pb] = acc[0];
            }
        }
        __syncthreads();

        // ---- elementwise (one (h-idx, batch) cell per thread 0..255)
        if (tid < 256) {
            const float gi_ = xgi + Gl[(     hi) * 17 + bb] + Gl[(64 +      hi) * 17 + bb];
            const float gf_ = xgf + Gl[(16 + hi) * 17 + bb] + Gl[(64 + 16 + hi) * 17 + bb];
            const float gg_ = xgg + Gl[(32 + hi) * 17 + bb] + Gl[(64 + 32 + hi) * 17 + bb];
            const float go_ = xgo + Gl[(48 + hi) * 17 + bb] + Gl[(64 + 48 + hi) * 17 + bb];
            const float i_ = 1.f / (1.f + expf(-gi_));
            const float f_ = 1.f / (1.f + expf(-gf_));
            const float g_ = tanhf(gg_);
            const float o_ = 1.f / (1.f + expf(-go_));
            c_state = f_ * c_state + i_ * g_;
            const float hv = o_ * tanhf(c_state);
            __hip_atomic_store(h_buf + (cur ^ 1) * (B_ * H_) + (size_t)bG * H_ + hs * 16 + hi,
                               hv, __ATOMIC_RELAXED, __HIP_MEMORY_SCOPE_AGENT);
            float pp = hv * wo;
            pp += shx(pp, 1); pp += shx(pp, 2); pp += shx(pp, 4); pp += shx(pp, 8);
            if (hi == 0) part[((size_t)t * B_ + bG) * 64 + hs] = pp;
        }

        // ---- fence-free group barrier (64 WGs sharing bg)
        asm volatile("s_waitcnt vmcnt(0)" ::: "memory");  // h stores acked at LLC
        __syncthreads();
        if (tid == 0) {
            if (__hip_atomic_fetch_add(cnt, 1, __ATOMIC_RELAXED,
                                       __HIP_MEMORY_SCOPE_AGENT) == 64 * (t + 1) - 1) {
                __hip_atomic_store(gen, t + 1, __ATOMIC_RELAXED,
                                   __HIP_MEMORY_SCOPE_AGENT);
            } else {
                while (__hip_atomic_load(gen, __ATOMIC_RELAXED,
                                         __HIP_MEMORY_SCOPE_AGENT) < t + 1) {}
            }
        }
        __syncthreads();
        cur ^= 1;
    }
}

// ---------------------------------------------------------------------------
// Kernel 4: out[b][t] = b_out + sum_hs part[t][b][hs]
// ---------------------------------------------------------------------------
__global__ void out_kernel(const float* __restrict__ part,
                           const float* __restrict__ b_out,
                           float* __restrict__ out) {
    const int g = blockIdx.x * blockDim.x + threadIdx.x;  // 16384
    const int t = g >> 6, b = g & 63;
    const float4* p4 = (const float4*)(part + ((size_t)t * B_ + b) * 64);
    float s = 0.f;
    #pragma unroll
    for (int i = 0; i < 16; ++i) {
        const float4 v = p4[i];
        s += v.x + v.y + v.z + v.w;
    }
    out[b * T_ + t] = s + b_out[0];
}

// ---------------------------------------------------------------------------
extern "C" void kernel_launch(void* const* d_in, const int* in_sizes, int n_in,
                              void* d_out, int out_size, void* d_ws, size_t ws_size,
                              hipStream_t stream) {
    const float* latent = (const float*)d_in[0];
    const float* W_lin  = (const float*)d_in[1];
    const float* b_lin  = (const float*)d_in[2];
    const float* W_ih   = (const float*)d_in[3];
    const float* W_hh   = (const float*)d_in[4];
    const float* b_ih   = (const float*)d_in[5];
    const float* b_hh   = (const float*)d_in[6];
    const float* W_out  = (const float*)d_in[7];
    const float* b_out  = (const float*)d_in[8];

    float* ws      = (float*)d_ws;
    float* hidden  = ws;                   // 65536
    float* x_gates = hidden  + 65536;      // 262144
    float* h_buf   = x_gates + 262144;     // 131072
    float* part    = h_buf   + 131072;     // 1048576
    int*   bar     = (int*)(part + 1048576);
    float* out     = (float*)d_out;

    hipMemsetAsync(h_buf, 0, (size_t)2 * B_ * H_ * sizeof(float), stream);
    hipMemsetAsync(bar, 0, 4 * 64 * sizeof(int), stream);

    const int lds_bytes = (16384 + 128 * 17) * sizeof(float);  // 74240
    hipFuncSetAttribute((const void*)lstm_kernel,
                        hipFuncAttributeMaxDynamicSharedMemorySize, lds_bytes);

    hidden_kernel<<<256, 256, 0, stream>>>(latent, W_lin, b_lin, hidden);
    xgates_kernel<<<1024, 256, 0, stream>>>(hidden, W_ih, b_ih, b_hh, x_gates);

    void* args[] = { (void*)&W_hh, (void*)&x_gates, (void*)&W_out,
                     (void*)&h_buf, (void*)&part, (void*)&bar };
    hipLaunchCooperativeKernel(reinterpret_cast<void*>(lstm_kernel),
                               dim3(NWG), dim3(1024), args, lds_bytes, stream);

    out_kernel<<<64, 256, 0, stream>>>(part, b_out, out);
}

// Round 7
// 1767.015 us; speedup vs baseline: 12.8942x; 1.7482x over previous
//
#include <hip/hip_runtime.h>
#include <hip/hip_cooperative_groups.h>

#define B_  64
#define L_  128
#define H_  1024
#define G4_ 4096
#define T_  256
#define NWG 256

typedef __attribute__((ext_vector_type(8))) short bf16x8;
typedef __attribute__((ext_vector_type(4))) float f32x4;

__device__ __forceinline__ float shx(float v, int m) { return __shfl_xor(v, m, 64); }

// fp32 -> bf16 (RNE) bit tricks
__device__ __forceinline__ unsigned rne_bf16(float x) {
    unsigned u = __builtin_bit_cast(unsigned, x);
    return (u + 0x7FFFu + ((u >> 16) & 1u)) >> 16;
}
__device__ __forceinline__ float bf16_to_f32(unsigned h) {
    return __builtin_bit_cast(float, h << 16);
}

// ---------------------------------------------------------------------------
// Kernel 1: hidden[b][j] = b_lin[j] + sum_l latent[b][l] * W_lin[j][l]
// ---------------------------------------------------------------------------
__global__ void hidden_kernel(const float* __restrict__ latent,
                              const float* __restrict__ W_lin,
                              const float* __restrict__ b_lin,
                              float* __restrict__ hidden) {
    const int wave = (blockIdx.x * blockDim.x + threadIdx.x) >> 6;
    const int lane = threadIdx.x & 63;
    for (int o = 0; o < 64; ++o) {
        const int out = wave * 64 + o;
        const int b = out >> 10, j = out & 1023;
        const float2 wv = *(const float2*)(W_lin + j * L_ + lane * 2);
        const float2 xv = *(const float2*)(latent + b * L_ + lane * 2);
        float p = wv.x * xv.x + wv.y * xv.y;
        #pragma unroll
        for (int m = 1; m < 64; m <<= 1) p += shx(p, m);
        if (lane == 0) hidden[out] = p + b_lin[j];
    }
}

// ---------------------------------------------------------------------------
// Kernel 2: x_gates[b][j] = b_ih[j] + b_hh[j] + sum_k hidden[b][k]*W_ih[j][k]
// ---------------------------------------------------------------------------
__global__ void xgates_kernel(const float* __restrict__ hidden,
                              const float* __restrict__ W_ih,
                              const float* __restrict__ b_ih,
                              const float* __restrict__ b_hh,
                              float* __restrict__ x_gates) {
    const int wave = (blockIdx.x * blockDim.x + threadIdx.x) >> 6;
    const int lane = threadIdx.x & 63;
    for (int o = 0; o < 64; ++o) {
        const int out = wave * 64 + o;
        const int b = out >> 12, j = out & 4095;
        float p = 0.f;
        #pragma unroll
        for (int q = 0; q < 4; ++q) {
            const float4 wv = *(const float4*)(W_ih + j * H_ + q * 256 + lane * 4);
            const float4 hv = *(const float4*)(hidden + b * H_ + q * 256 + lane * 4);
            p += wv.x * hv.x + wv.y * hv.y + wv.z * hv.z + wv.w * hv.w;
        }
        #pragma unroll
        for (int m = 1; m < 64; m <<= 1) p += shx(p, m);
        if (lane == 0) x_gates[out] = p + b_ih[j] + b_hh[j];
    }
}

// ---------------------------------------------------------------------------
// Kernel 3: sequential LSTM — MFMA bf16-split (3-product) edition.
// Grid: 256 WGs = 64 h-slices (hs) x 4 batch groups (bg, 16 batches).
// 1024 thr = 16 waves: wave wv -> (tau = wv&3 = gate/tile, kq = wv>>2).
// Per WG/step: G[64r][16b] = Whh_slice[64x1024] . h^T[1024x16] via
// mfma_f32_16x16x32_bf16, weights as per-thread bf16 hi/lo A-frags (one-time),
// h staged from LLC (packed hi16|lo16 u32) into two swizzled LDS bf16 planes.
// acc = Ahi*Bhi + Ahi*Blo + Alo*Bhi (fp32 accum) -> ~fp32 accuracy.
// Cross-wave (kq) reduce via LDS tile, elementwise with c in regs,
// fence-free relaxed-atomic group barrier (proven round 6).
// ---------------------------------------------------------------------------
__global__ void __launch_bounds__(1024, 4)
lstm_kernel(const float* __restrict__ W_hh,     // [4096][1024] fp32
            const float* __restrict__ x_gates,  // [64][4096]
            const float* __restrict__ W_out,    // [1024]
            unsigned* __restrict__ h_buf,       // [2][64][1024] packed hi16|lo16
            float* __restrict__ part,           // [T][64 b][64 hs]
            int*   __restrict__ bar)            // [4][64] ints, memset 0
{
    extern __shared__ float smem[];
    // bytes [0,32768): Hhi [16 b][128 granule-slots][8 bf16]  (swizzled)
    // bytes [32768,65536): Hlo same layout
    // dwords [16384, 16384+4352): Gred [16 tile*kq][16 row][17]
    unsigned* Hhi32 = (unsigned*)smem;
    unsigned* Hlo32 = (unsigned*)smem + 8192;
    float*    Gred  = smem + 16384;

    const int tid = threadIdx.x;
    const int l   = tid & 63;
    const int wv  = tid >> 6;
    const int tau = wv & 3;         // gate / row-tile
    const int kq  = wv >> 2;        // k-quarter (8 ksteps of 32)
    const int hs  = blockIdx.x >> 2;
    const int bg  = blockIdx.x & 3;
    const int row16 = l & 15;       // A row / D col depending on phase
    const int kg    = l >> 4;       // k-chunk within kstep

    // ---- one-time: weights -> bf16 hi/lo A-fragments in VGPRs
    bf16x8 Ahi[8], Alo[8];
    {
        const float* wrow = W_hh + (size_t)(tau * H_ + hs * 16 + row16) * H_;
        #pragma unroll
        for (int s = 0; s < 8; ++s) {
            const int ks = kq * 8 + s;
            const float* p = wrow + ks * 32 + kg * 8;
            const float4 f0 = *(const float4*)p;
            const float4 f1 = *(const float4*)(p + 4);
            const float w[8] = {f0.x, f0.y, f0.z, f0.w, f1.x, f1.y, f1.z, f1.w};
            #pragma unroll
            for (int j = 0; j < 8; ++j) {
                const unsigned hb = rne_bf16(w[j]);
                const float lo = w[j] - bf16_to_f32(hb);
                Ahi[s][j] = (short)hb;
                Alo[s][j] = (short)rne_bf16(lo);
            }
        }
    }

    // ---- elementwise constants (threads 0..255: bb = tid>>4, hix = tid&15)
    const int bb  = tid >> 4;
    const int hix = tid & 15;
    const int bG  = bg * 16 + bb;
    float xgi = 0, xgf = 0, xgg = 0, xgo = 0, wo = 0;
    if (tid < 256) {
        const float* xg = x_gates + (size_t)bG * G4_ + hs * 16 + hix;
        xgi = xg[0]; xgf = xg[H_]; xgg = xg[2 * H_]; xgo = xg[3 * H_];
        wo  = W_out[hs * 16 + hix];
    }
    float c_state = 0.f;

    int* cnt = bar + bg * 64;
    int* gen = bar + bg * 64 + 32;

    int cur = 0;
    for (int t = 0; t < T_; ++t) {
        // ---- stage: LLC (packed u32 pairs as u64) -> two swizzled LDS planes
        {
            const int b = wv;   // WG-local batch this wave stages
            const unsigned long long* src =
                (const unsigned long long*)(h_buf + (size_t)cur * (B_ * H_) +
                                            (size_t)(bg * 16 + b) * H_);
            #pragma unroll
            for (int i = 0; i < 8; ++i) {
                const int d = i * 64 + l;              // k-pair index 0..511
                const unsigned long long v =
                    __hip_atomic_load(src + d, __ATOMIC_RELAXED,
                                      __HIP_MEMORY_SCOPE_AGENT);
                const unsigned p0 = (unsigned)v;          // element k = 2d
                const unsigned p1 = (unsigned)(v >> 32);  // element k = 2d+1
                const int dw = b * 512 + (((d >> 2) ^ (b & 7)) << 2) + (d & 3);
                Hhi32[dw] = (p1 & 0xFFFF0000u) | (p0 >> 16);
                Hlo32[dw] = ((p1 & 0xFFFFu) << 16) | (p0 & 0xFFFFu);
            }
        }
        __syncthreads();

        // ---- MFMA phase: 8 ksteps x {2 ds_read_b128, 3 mfma}
        {
            f32x4 acc = {0.f, 0.f, 0.f, 0.f};
            const char* HhiB = (const char*)smem;
            const char* HloB = (const char*)smem + 32768;
            #pragma unroll
            for (int s = 0; s < 8; ++s) {
                const int ks  = kq * 8 + s;
                const int off = row16 * 2048 + (((ks * 4 + kg) ^ (row16 & 7)) << 4);
                const bf16x8 Bhi = *(const bf16x8*)(HhiB + off);
                const bf16x8 Blo = *(const bf16x8*)(HloB + off);
                acc = __builtin_amdgcn_mfma_f32_16x16x32_bf16(Ahi[s], Bhi, acc, 0, 0, 0);
                acc = __builtin_amdgcn_mfma_f32_16x16x32_bf16(Ahi[s], Blo, acc, 0, 0, 0);
                acc = __builtin_amdgcn_mfma_f32_16x16x32_bf16(Alo[s], Bhi, acc, 0, 0, 0);
            }
            // D: col = l&15 (batch), row = kg*4 + r (h-idx within tile)
            #pragma unroll
            for (int r = 0; r < 4; ++r)
                Gred[((tau * 4 + kq) * 16 + kg * 4 + r) * 17 + row16] = acc[r];
        }
        __syncthreads();

        // ---- reduce over kq + elementwise (one (h-idx, batch) per thread)
        if (tid < 256) {
            float gs[4];
            #pragma unroll
            for (int g = 0; g < 4; ++g) {
                float s = 0.f;
                #pragma unroll
                for (int q = 0; q < 4; ++q)
                    s += Gred[((g * 4 + q) * 16 + hix) * 17 + bb];
                gs[g] = s;
            }
            const float gi_ = xgi + gs[0];
            const float gf_ = xgf + gs[1];
            const float gg_ = xgg + gs[2];
            const float go_ = xgo + gs[3];
            const float i_ = 1.f / (1.f + expf(-gi_));
            const float f_ = 1.f / (1.f + expf(-gf_));
            const float g_ = tanhf(gg_);
            const float o_ = 1.f / (1.f + expf(-go_));
            c_state = f_ * c_state + i_ * g_;
            const float hv = o_ * tanhf(c_state);
            // pack h as bf16 hi/lo and store to LLC (relaxed)
            const unsigned hb = rne_bf16(hv);
            const float lo = hv - bf16_to_f32(hb);
            const unsigned packed = (hb << 16) | rne_bf16(lo);
            __hip_atomic_store(h_buf + (size_t)(cur ^ 1) * (B_ * H_) +
                               (size_t)bG * H_ + hs * 16 + hix,
                               packed, __ATOMIC_RELAXED, __HIP_MEMORY_SCOPE_AGENT);
            float pp = hv * wo;
            pp += shx(pp, 1); pp += shx(pp, 2); pp += shx(pp, 4); pp += shx(pp, 8);
            if (hix == 0) part[((size_t)t * B_ + bG) * 64 + hs] = pp;
        }

        // ---- fence-free group barrier (64 WGs sharing bg) — proven round 6
        asm volatile("s_waitcnt vmcnt(0)" ::: "memory");
        __syncthreads();
        if (tid == 0) {
            if (__hip_atomic_fetch_add(cnt, 1, __ATOMIC_RELAXED,
                                       __HIP_MEMORY_SCOPE_AGENT) == 64 * (t + 1) - 1) {
                __hip_atomic_store(gen, t + 1, __ATOMIC_RELAXED,
                                   __HIP_MEMORY_SCOPE_AGENT);
            } else {
                while (__hip_atomic_load(gen, __ATOMIC_RELAXED,
                                         __HIP_MEMORY_SCOPE_AGENT) < t + 1) {}
            }
        }
        __syncthreads();
        cur ^= 1;
    }
}

// ---------------------------------------------------------------------------
// Kernel 4: out[b][t] = b_out + sum_hs part[t][b][hs]
// ---------------------------------------------------------------------------
__global__ void out_kernel(const float* __restrict__ part,
                           const float* __restrict__ b_out,
                           float* __restrict__ out) {
    const int g = blockIdx.x * blockDim.x + threadIdx.x;  // 16384
    const int t = g >> 6, b = g & 63;
    const float4* p4 = (const float4*)(part + ((size_t)t * B_ + b) * 64);
    float s = 0.f;
    #pragma unroll
    for (int i = 0; i < 16; ++i) {
        const float4 v = p4[i];
        s += v.x + v.y + v.z + v.w;
    }
    out[b * T_ + t] = s + b_out[0];
}

// ---------------------------------------------------------------------------
extern "C" void kernel_launch(void* const* d_in, const int* in_sizes, int n_in,
                              void* d_out, int out_size, void* d_ws, size_t ws_size,
                              hipStream_t stream) {
    const float* latent = (const float*)d_in[0];
    const float* W_lin  = (const float*)d_in[1];
    const float* b_lin  = (const float*)d_in[2];
    const float* W_ih   = (const float*)d_in[3];
    const float* W_hh   = (const float*)d_in[4];
    const float* b_ih   = (const float*)d_in[5];
    const float* b_hh   = (const float*)d_in[6];
    const float* W_out  = (const float*)d_in[7];
    const float* b_out  = (const float*)d_in[8];

    float* ws      = (float*)d_ws;
    float* hidden  = ws;                        // 65536 f
    float* x_gates = hidden  + 65536;           // 262144 f
    unsigned* h_buf = (unsigned*)(x_gates + 262144);  // 131072 u32
    float* part    = (float*)(h_buf + 131072);  // 1048576 f
    int*   bar     = (int*)(part + 1048576);
    float* out     = (float*)d_out;

    hipMemsetAsync(h_buf, 0, (size_t)2 * B_ * H_ * sizeof(unsigned), stream);
    hipMemsetAsync(bar, 0, 4 * 64 * sizeof(int), stream);

    const int lds_bytes = 65536 + 4352 * 4;  // H planes + Gred = 82944
    hipFuncSetAttribute((const void*)lstm_kernel,
                        hipFuncAttributeMaxDynamicSharedMemorySize, lds_bytes);

    hidden_kernel<<<256, 256, 0, stream>>>(latent, W_lin, b_lin, hidden);
    xgates_kernel<<<1024, 256, 0, stream>>>(hidden, W_ih, b_ih, b_hh, x_gates);

    void* args[] = { (void*)&W_hh, (void*)&x_gates, (void*)&W_out,
                     (void*)&h_buf, (void*)&part, (void*)&bar };
    hipLaunchCooperativeKernel(reinterpret_cast<void*>(lstm_kernel),
                               dim3(NWG), dim3(1024), args, lds_bytes, stream);

    out_kernel<<<64, 256, 0, stream>>>(part, b_out, out);
}

// Round 8
// 1538.570 us; speedup vs baseline: 14.8087x; 1.1485x over previous
//
#include <hip/hip_runtime.h>

#define B_  64
#define L_  128
#define H_  1024
#define G4_ 4096
#define T_  256
#define NWG 256

typedef __attribute__((ext_vector_type(8))) short bf16x8;
typedef __attribute__((ext_vector_type(4))) float f32x4;
typedef __attribute__((ext_vector_type(4))) unsigned u32x4;

__device__ __forceinline__ float shx(float v, int m) { return __shfl_xor(v, m, 64); }

__device__ __forceinline__ unsigned rne_bf16(float x) {
    unsigned u = __builtin_bit_cast(unsigned, x);
    return (u + 0x7FFFu + ((u >> 16) & 1u)) >> 16;
}
__device__ __forceinline__ float bf16_to_f32(unsigned h) {
    return __builtin_bit_cast(float, h << 16);
}

// ---------------------------------------------------------------------------
// Kernel 1: hidden[b][j] = b_lin[j] + sum_l latent[b][l] * W_lin[j][l]
// ---------------------------------------------------------------------------
__global__ void hidden_kernel(const float* __restrict__ latent,
                              const float* __restrict__ W_lin,
                              const float* __restrict__ b_lin,
                              float* __restrict__ hidden) {
    const int wave = (blockIdx.x * blockDim.x + threadIdx.x) >> 6;
    const int lane = threadIdx.x & 63;
    for (int o = 0; o < 64; ++o) {
        const int out = wave * 64 + o;
        const int b = out >> 10, j = out & 1023;
        const float2 wv = *(const float2*)(W_lin + j * L_ + lane * 2);
        const float2 xv = *(const float2*)(latent + b * L_ + lane * 2);
        float p = wv.x * xv.x + wv.y * xv.y;
        #pragma unroll
        for (int m = 1; m < 64; m <<= 1) p += shx(p, m);
        if (lane == 0) hidden[out] = p + b_lin[j];
    }
}

// ---------------------------------------------------------------------------
// Kernel 2: x_gates[b][j] = b_ih[j] + b_hh[j] + sum_k hidden[b][k]*W_ih[j][k]
// 4096 blocks x 256 thr = 16384 waves x 16 outputs.
// ---------------------------------------------------------------------------
__global__ void xgates_kernel(const float* __restrict__ hidden,
                              const float* __restrict__ W_ih,
                              const float* __restrict__ b_ih,
                              const float* __restrict__ b_hh,
                              float* __restrict__ x_gates) {
    const int wave = (blockIdx.x * blockDim.x + threadIdx.x) >> 6;
    const int lane = threadIdx.x & 63;
    for (int o = 0; o < 16; ++o) {
        const int out = wave * 16 + o;
        const int b = out >> 12, j = out & 4095;
        float p = 0.f;
        #pragma unroll
        for (int q = 0; q < 4; ++q) {
            const float4 wv = *(const float4*)(W_ih + j * H_ + q * 256 + lane * 4);
            const float4 hv = *(const float4*)(hidden + b * H_ + q * 256 + lane * 4);
            p += wv.x * hv.x + wv.y * hv.y + wv.z * hv.z + wv.w * hv.w;
        }
        #pragma unroll
        for (int m = 1; m < 64; m <<= 1) p += shx(p, m);
        if (lane == 0) x_gates[out] = p + b_ih[j] + b_hh[j];
    }
}

// ---------------------------------------------------------------------------
// Kernel 3: sequential LSTM — MFMA bf16-split, LDS-lean, RMW-free barrier.
// Grid: 256 WGs = 64 hs x 4 bg. 16 waves = 8 kq (128 k each) x 2 gate-pairs.
// h exchanged via LLC as packed u32 {bf16hi|bf16lo}; staged RAW into LDS
// (b64 writes, granule-XOR-swizzled); hi/lo split on read via v_perm_b32.
// Each B-frag pair feeds 6 MFMAs (2 gates x 3-product split).
// Barrier: per-WG arrival slot (64B apart) + wave-0 lane-parallel poll.
// ---------------------------------------------------------------------------
__global__ void __launch_bounds__(1024, 2)
lstm_kernel(const float* __restrict__ W_hh,     // [4096][1024] fp32
            const float* __restrict__ x_gates,  // [64][4096]
            const float* __restrict__ W_out,    // [1024]
            unsigned* __restrict__ h_buf,       // [2][64][1024] packed hi16|lo16
            float* __restrict__ part,           // [T][64 b][64 hs]
            int*   __restrict__ bar)            // [4][1024] ints (slot stride 16)
{
    extern __shared__ float smem[];
    unsigned* Hraw = (unsigned*)smem;        // [16 b][1024 elem] u32, swizzled
    float*    Gred = smem + 16384;           // [4 g][8 q][16 b][20]

    const int tid = threadIdx.x;
    const int l   = tid & 63;
    const int wv  = tid >> 6;       // 16 waves
    const int kq  = wv >> 1;        // 0..7 : k-eighth (4 ksteps of 32)
    const int tp  = wv & 1;         // 0..1 : gates {2tp, 2tp+1}
    const int hs  = blockIdx.x >> 2;
    const int bg  = blockIdx.x & 3;
    const int row16 = l & 15;       // A row / B col / D col
    const int kg    = l >> 4;       // k-chunk within kstep

    // ---- one-time: A-frags (2 gates x 4 ksteps x hi/lo) in VGPRs
    bf16x8 Ahi[2][4], Alo[2][4];
    #pragma unroll
    for (int g = 0; g < 2; ++g) {
        const int gate = tp * 2 + g;
        const float* wrow = W_hh + (size_t)(gate * H_ + hs * 16 + row16) * H_;
        #pragma unroll
        for (int s = 0; s < 4; ++s) {
            const int ks = kq * 4 + s;
            const float* p = wrow + ks * 32 + kg * 8;
            const float4 f0 = *(const float4*)p;
            const float4 f1 = *(const float4*)(p + 4);
            const float w[8] = {f0.x, f0.y, f0.z, f0.w, f1.x, f1.y, f1.z, f1.w};
            #pragma unroll
            for (int j = 0; j < 8; ++j) {
                const unsigned hb = rne_bf16(w[j]);
                const float lo = w[j] - bf16_to_f32(hb);
                Ahi[g][s][j] = (short)hb;
                Alo[g][s][j] = (short)rne_bf16(lo);
            }
        }
    }

    // ---- elementwise constants (threads 0..255: bb = tid>>4, hix = tid&15)
    const int bb  = tid >> 4;
    const int hix = tid & 15;
    const int bG  = bg * 16 + bb;
    float xgi = 0, xgf = 0, xgg = 0, xgo = 0, wo = 0;
    if (tid < 256) {
        const float* xg = x_gates + (size_t)bG * G4_ + hs * 16 + hix;
        xgi = xg[0]; xgf = xg[H_]; xgg = xg[2 * H_]; xgo = xg[3 * H_];
        wo  = W_out[hs * 16 + hix];
    }
    float c_state = 0.f;

    unsigned long long* H64 = (unsigned long long*)Hraw;
    int cur = 0;
    for (int t = 0; t < T_; ++t) {
        // ---- stage: wave wv loads batch wv (raw u64 pairs) -> swizzled LDS
        {
            const unsigned long long* src =
                (const unsigned long long*)(h_buf + (size_t)cur * (B_ * H_) +
                                            (size_t)(bg * 16 + wv) * H_);
            unsigned long long v[8];
            #pragma unroll
            for (int i = 0; i < 8; ++i)
                v[i] = __hip_atomic_load(src + i * 64 + l, __ATOMIC_RELAXED,
                                         __HIP_MEMORY_SCOPE_AGENT);
            #pragma unroll
            for (int i = 0; i < 8; ++i) {
                const int d = i * 64 + l;            // u64 idx = elems {2d,2d+1}
                H64[wv * 512 + (((d >> 1) ^ (wv & 7)) << 1) + (d & 1)] = v[i];
            }
        }
        __syncthreads();

        // ---- MFMA: 4 ksteps x {2 ds_read_b128, 8 v_perm, 6 mfma}
        {
            f32x4 acc0 = {0.f, 0.f, 0.f, 0.f};
            f32x4 acc1 = {0.f, 0.f, 0.f, 0.f};
            const unsigned* Hb = Hraw + row16 * 1024;
            const int sw = row16 & 7;
            #pragma unroll
            for (int s = 0; s < 4; ++s) {
                const int g0 = (kq * 4 + s) * 8 + kg * 2;   // granule index
                const u32x4 ra = *(const u32x4*)(Hb + ((g0 ^ sw) << 2));
                const u32x4 rb = *(const u32x4*)(Hb + (((g0 + 1) ^ sw) << 2));
                u32x4 bh, bl;
                bh[0] = __builtin_amdgcn_perm(ra[1], ra[0], 0x07060302u);
                bl[0] = __builtin_amdgcn_perm(ra[1], ra[0], 0x05040100u);
                bh[1] = __builtin_amdgcn_perm(ra[3], ra[2], 0x07060302u);
                bl[1] = __builtin_amdgcn_perm(ra[3], ra[2], 0x05040100u);
                bh[2] = __builtin_amdgcn_perm(rb[1], rb[0], 0x07060302u);
                bl[2] = __builtin_amdgcn_perm(rb[1], rb[0], 0x05040100u);
                bh[3] = __builtin_amdgcn_perm(rb[3], rb[2], 0x07060302u);
                bl[3] = __builtin_amdgcn_perm(rb[3], rb[2], 0x05040100u);
                const bf16x8 Bhi = __builtin_bit_cast(bf16x8, bh);
                const bf16x8 Blo = __builtin_bit_cast(bf16x8, bl);
                acc0 = __builtin_amdgcn_mfma_f32_16x16x32_bf16(Ahi[0][s], Bhi, acc0, 0, 0, 0);
                acc0 = __builtin_amdgcn_mfma_f32_16x16x32_bf16(Ahi[0][s], Blo, acc0, 0, 0, 0);
                acc0 = __builtin_amdgcn_mfma_f32_16x16x32_bf16(Alo[0][s], Bhi, acc0, 0, 0, 0);
                acc1 = __builtin_amdgcn_mfma_f32_16x16x32_bf16(Ahi[1][s], Bhi, acc1, 0, 0, 0);
                acc1 = __builtin_amdgcn_mfma_f32_16x16x32_bf16(Ahi[1][s], Blo, acc1, 0, 0, 0);
                acc1 = __builtin_amdgcn_mfma_f32_16x16x32_bf16(Alo[1][s], Bhi, acc1, 0, 0, 0);
            }
            // D: col = l&15 (batch), rows = kg*4..+3 -> b128 into Gred
            *(f32x4*)(Gred + (((tp * 2 + 0) * 8 + kq) * 16 + row16) * 20 + kg * 4) = acc0;
            *(f32x4*)(Gred + (((tp * 2 + 1) * 8 + kq) * 16 + row16) * 20 + kg * 4) = acc1;
        }
        __syncthreads();

        // ---- reduce over kq + elementwise
        if (tid < 256) {
            float gs[4];
            #pragma unroll
            for (int g = 0; g < 4; ++g) {
                float s = 0.f;
                #pragma unroll
                for (int q = 0; q < 8; ++q)
                    s += Gred[((g * 8 + q) * 16 + bb) * 20 + hix];
                gs[g] = s;
            }
            const float gi_ = xgi + gs[0];
            const float gf_ = xgf + gs[1];
            const float gg_ = xgg + gs[2];
            const float go_ = xgo + gs[3];
            const float i_ = 1.f / (1.f + expf(-gi_));
            const float f_ = 1.f / (1.f + expf(-gf_));
            const float g_ = tanhf(gg_);
            const float o_ = 1.f / (1.f + expf(-go_));
            c_state = f_ * c_state + i_ * g_;
            const float hv = o_ * tanhf(c_state);
            const unsigned hb = rne_bf16(hv);
            const float lo = hv - bf16_to_f32(hb);
            const unsigned packed = (hb << 16) | rne_bf16(lo);
            __hip_atomic_store(h_buf + (size_t)(cur ^ 1) * (B_ * H_) +
                               (size_t)bG * H_ + hs * 16 + hix,
                               packed, __ATOMIC_RELAXED, __HIP_MEMORY_SCOPE_AGENT);
            float pp = hv * wo;
            pp += shx(pp, 1); pp += shx(pp, 2); pp += shx(pp, 4); pp += shx(pp, 8);
            if (hix == 0) part[((size_t)t * B_ + bG) * 64 + hs] = pp;
        }

        // ---- RMW-free group barrier: arrival slots + lane-parallel poll
        asm volatile("s_waitcnt vmcnt(0)" ::: "memory");  // own h stores acked
        __syncthreads();                                  // all 4 waves' stores done
        if (tid == 0)
            __hip_atomic_store(bar + bg * 1024 + hs * 16, t + 1,
                               __ATOMIC_RELAXED, __HIP_MEMORY_SCOPE_AGENT);
        if (tid < 64) {
            const int* sp = bar + bg * 1024 + tid * 16;   // lane i polls WG i's slot
            while (__hip_atomic_load(sp, __ATOMIC_RELAXED,
                                     __HIP_MEMORY_SCOPE_AGENT) < t + 1)
                __builtin_amdgcn_s_sleep(1);
        }
        __syncthreads();
        cur ^= 1;
    }
}

// ---------------------------------------------------------------------------
// Kernel 4: out[b][t] = b_out + sum_hs part[t][b][hs]
// ---------------------------------------------------------------------------
__global__ void out_kernel(const float* __restrict__ part,
                           const float* __restrict__ b_out,
                           float* __restrict__ out) {
    const int g = blockIdx.x * blockDim.x + threadIdx.x;  // 16384
    const int t = g >> 6, b = g & 63;
    const float4* p4 = (const float4*)(part + ((size_t)t * B_ + b) * 64);
    float s = 0.f;
    #pragma unroll
    for (int i = 0; i < 16; ++i) {
        const float4 v = p4[i];
        s += v.x + v.y + v.z + v.w;
    }
    out[b * T_ + t] = s + b_out[0];
}

// ---------------------------------------------------------------------------
extern "C" void kernel_launch(void* const* d_in, const int* in_sizes, int n_in,
                              void* d_out, int out_size, void* d_ws, size_t ws_size,
                              hipStream_t stream) {
    const float* latent = (const float*)d_in[0];
    const float* W_lin  = (const float*)d_in[1];
    const float* b_lin  = (const float*)d_in[2];
    const float* W_ih   = (const float*)d_in[3];
    const float* W_hh   = (const float*)d_in[4];
    const float* b_ih   = (const float*)d_in[5];
    const float* b_hh   = (const float*)d_in[6];
    const float* W_out  = (const float*)d_in[7];
    const float* b_out  = (const float*)d_in[8];

    float* ws      = (float*)d_ws;
    float* hidden  = ws;                        // 65536 f
    float* x_gates = hidden  + 65536;           // 262144 f
    unsigned* h_buf = (unsigned*)(x_gates + 262144);  // 131072 u32
    float* part    = (float*)(h_buf + 131072);  // 1048576 f
    int*   bar     = (int*)(part + 1048576);    // 4096 ints
    float* out     = (float*)d_out;

    hipMemsetAsync(h_buf, 0, (size_t)2 * B_ * H_ * sizeof(unsigned), stream);
    hipMemsetAsync(bar, 0, 4 * 1024 * sizeof(int), stream);

    const int lds_bytes = (16384 + 4 * 8 * 16 * 20) * sizeof(float);  // 106496
    hipFuncSetAttribute((const void*)lstm_kernel,
                        hipFuncAttributeMaxDynamicSharedMemorySize, lds_bytes);

    hidden_kernel<<<256, 256, 0, stream>>>(latent, W_lin, b_lin, hidden);
    xgates_kernel<<<4096, 256, 0, stream>>>(hidden, W_ih, b_ih, b_hh, x_gates);

    void* args[] = { (void*)&W_hh, (void*)&x_gates, (void*)&W_out,
                     (void*)&h_buf, (void*)&part, (void*)&bar };
    hipLaunchCooperativeKernel(reinterpret_cast<void*>(lstm_kernel),
                               dim3(NWG), dim3(1024), args, lds_bytes, stream);

    out_kernel<<<64, 256, 0, stream>>>(part, b_out, out);
}